// Round 6
// baseline (3681.404 us; speedup 1.0000x reference)
//
#include <hip/hip_runtime.h>
#include <hip/hip_bf16.h>

#define N_NODES 8000
#define N_EDGES 128000
#define RS8   0.35355339059327373f
#define RS64  0.125f
#define RS128 0.08838834764831845f
#define C1    0.005524271728019903f   /* (1/sqrt(128))/16 */
#define NORM  0.02795084971874737f    /* 1/sqrt(1280) */

__device__ __forceinline__ float siluf(float v){ return v / (1.f + __expf(-v)); }
__device__ __forceinline__ unsigned short f2bf(float v){
  unsigned int b = __float_as_uint(v);
  b += 0x7fffu + ((b >> 16) & 1u);
  return (unsigned short)(b >> 16);
}
__device__ __forceinline__ float bf2f(unsigned int h){
  union{unsigned int u; float f;} z; z.u = h << 16; return z.f;
}
__device__ __forceinline__ float lo2f(unsigned int p){  // low bf16 of packed u32
  union{unsigned int u; float f;} z; z.u = p << 16; return z.f;
}
__device__ __forceinline__ float hi2f(unsigned int p){  // high bf16 of packed u32
  union{unsigned int u; float f;} z; z.u = p & 0xffff0000u; return z.f;
}

// Wt element = 24 ushorts (48 B) per (lg,u,w); per-u stride = 128 w * 48 B = 6144 B.
#define WT_U_STRIDE_U4 384   /* 6144 / sizeof(uint4) */

// ---------------------------------------------------------------- K1: x = node_feats @ W_up * RS128
__global__ void __launch_bounds__(256) k_up(const float* __restrict__ nf,
                                            const float* __restrict__ Wup,
                                            float* __restrict__ x){
  __shared__ float f[2][128];
  const int t = threadIdx.x;
  const int nl = t >> 7, c = t & 127;
  const int n = blockIdx.x * 2 + nl;
  f[nl][c] = nf[(size_t)n * 128 + c];
  __syncthreads();
  float acc = 0.f;
  #pragma unroll 8
  for(int k = 0; k < 128; ++k) acc += f[nl][k] * Wup[k * 128 + c];
  x[(size_t)n * 128 + c] = acc * RS128;
}

// ---------------------------------------------------------------- K2: edge MLP -> tp_weights (bf16, cutoff folded)
__device__ __forceinline__ void gemm64(const float* __restrict__ hin, const float* __restrict__ Wb,
                                       int eb, int cb, float4 acc[4]){
  #pragma unroll
  for(int i = 0; i < 4; ++i) acc[i] = make_float4(0.f,0.f,0.f,0.f);
  #pragma unroll 2
  for(int k = 0; k < 64; k += 4){
    float4 w0 = *(const float4*)&Wb[(k+0)*64 + cb];
    float4 w1 = *(const float4*)&Wb[(k+1)*64 + cb];
    float4 w2 = *(const float4*)&Wb[(k+2)*64 + cb];
    float4 w3 = *(const float4*)&Wb[(k+3)*64 + cb];
    #pragma unroll
    for(int i = 0; i < 4; ++i){
      float4 h = *(const float4*)&hin[(eb+i)*64 + k];
      acc[i].x += h.x*w0.x + h.y*w1.x + h.z*w2.x + h.w*w3.x;
      acc[i].y += h.x*w0.y + h.y*w1.y + h.z*w2.y + h.w*w3.y;
      acc[i].z += h.x*w0.z + h.y*w1.z + h.z*w2.z + h.w*w3.z;
      acc[i].w += h.x*w0.w + h.y*w1.w + h.z*w2.w + h.w*w3.w;
    }
  }
}

__global__ void __launch_bounds__(256) k_mlp(
    const float* __restrict__ efg, const float* __restrict__ cut,
    const float* __restrict__ W1g, const float* __restrict__ W2g,
    const float* __restrict__ W3g, const float* __restrict__ W4g,
    __hip_bfloat16* __restrict__ tpw){
  __shared__ float ef[512];     // 64 edges x 8
  __shared__ float W1s[512];
  __shared__ float hA[4096];    // 64 x 64
  __shared__ float hB[4096];
  __shared__ float Wb[4096];
  __shared__ float co[64];
  const int t = threadIdx.x;
  const int e0 = blockIdx.x * 64;
  ((float2*)ef)[t]  = ((const float2*)(efg + (size_t)e0 * 8))[t];
  ((float2*)W1s)[t] = ((const float2*)W1g)[t];
  if(t < 64) co[t] = cut[e0 + t];
  __syncthreads();
  const int et = t >> 4, ct = t & 15;
  const int eb = et * 4, cb = ct * 4;
  // L1: (64x8)@(8x64) * RS8 -> silu -> hA
  {
    float4 acc[4];
    #pragma unroll
    for(int i = 0; i < 4; ++i) acc[i] = make_float4(0.f,0.f,0.f,0.f);
    #pragma unroll
    for(int k = 0; k < 8; ++k){
      float4 wv = *(const float4*)&W1s[k*64 + cb];
      #pragma unroll
      for(int i = 0; i < 4; ++i){
        float h = ef[(eb+i)*8 + k];
        acc[i].x += h*wv.x; acc[i].y += h*wv.y; acc[i].z += h*wv.z; acc[i].w += h*wv.w;
      }
    }
    #pragma unroll
    for(int i = 0; i < 4; ++i){
      float4 r;
      r.x = siluf(acc[i].x*RS8); r.y = siluf(acc[i].y*RS8);
      r.z = siluf(acc[i].z*RS8); r.w = siluf(acc[i].w*RS8);
      *(float4*)&hA[(eb+i)*64 + cb] = r;
    }
  }
  __syncthreads();
  #pragma unroll
  for(int r = 0; r < 8; ++r) ((float2*)Wb)[t + 256*r] = ((const float2*)W2g)[t + 256*r];
  __syncthreads();
  { // L2: hA -> hB
    float4 a[4]; gemm64(hA, Wb, eb, cb, a);
    #pragma unroll
    for(int i = 0; i < 4; ++i){
      float4 r;
      r.x = siluf(a[i].x*RS64); r.y = siluf(a[i].y*RS64);
      r.z = siluf(a[i].z*RS64); r.w = siluf(a[i].w*RS64);
      *(float4*)&hB[(eb+i)*64 + cb] = r;
    }
  }
  __syncthreads();
  #pragma unroll
  for(int r = 0; r < 8; ++r) ((float2*)Wb)[t + 256*r] = ((const float2*)W3g)[t + 256*r];
  __syncthreads();
  { // L3: hB -> hA
    float4 a[4]; gemm64(hB, Wb, eb, cb, a);
    #pragma unroll
    for(int i = 0; i < 4; ++i){
      float4 r;
      r.x = siluf(a[i].x*RS64); r.y = siluf(a[i].y*RS64);
      r.z = siluf(a[i].z*RS64); r.w = siluf(a[i].w*RS64);
      *(float4*)&hA[(eb+i)*64 + cb] = r;
    }
  }
  __syncthreads();
  // L4: hA(64x64) @ W4(64x512) in 8 chunks of 64 cols; *RS64*cutoff -> bf16
  for(int ch = 0; ch < 8; ++ch){
    #pragma unroll
    for(int r = 0; r < 16; ++r){
      int idx = t + 256*r;
      Wb[idx] = W4g[(idx >> 6) * 512 + ch * 64 + (idx & 63)];
    }
    __syncthreads();
    float4 a[4]; gemm64(hA, Wb, eb, cb, a);
    #pragma unroll
    for(int i = 0; i < 4; ++i){
      float cf = co[eb + i] * RS64;
      ushort4 pk;
      pk.x = f2bf(a[i].x * cf); pk.y = f2bf(a[i].y * cf);
      pk.z = f2bf(a[i].z * cf); pk.w = f2bf(a[i].w * cf);
      *(ushort4*)((unsigned short*)tpw + (size_t)(e0 + eb + i) * 512 + ch * 64 + cb) = pk;
    }
    __syncthreads();
  }
}

// ---------------------------------------------------------------- Wm[m][u][u'] = W_lin[l(m)][u][u'] * C1
__global__ void k_wm(const float* __restrict__ Wlin, float* __restrict__ Wm){
  int idx = blockIdx.x * 256 + threadIdx.x;
  if(idx >= 16 * 16384) return;
  int m = idx >> 14;
  int l = (m == 0) ? 0 : (m < 4) ? 1 : (m < 9) ? 2 : 3;
  Wm[idx] = Wlin[l * 16384 + (idx & 16383)] * C1;
}

// ---------------------------------------------------------------- W_skip -> transposed bf16
// Wt[lg][u][w][p][12v] ushort, lg0 pairs (l0,l3), lg1 pairs (l1,l2); v=10,11 zero pad.
__global__ void __launch_bounds__(256) k_wcvt(const float* __restrict__ Ws,
                                              unsigned short* __restrict__ Wt){
  int tid = blockIdx.x * 256 + threadIdx.x;   // 32768 = 2 lg * 128 u * 128 w
  int lg = tid >> 14, u = (tid >> 7) & 127, w = tid & 127;
  unsigned short buf[24];
  #pragma unroll
  for(int p = 0; p < 2; ++p){
    int l = (lg == 0) ? (p == 0 ? 0 : 3) : (p == 0 ? 1 : 2);
    #pragma unroll
    for(int v = 0; v < 10; ++v)
      buf[p * 12 + v] = f2bf(Ws[((size_t)(l * 128 + u) * 10 + v) * 128 + w]);
    buf[p * 12 + 10] = 0; buf[p * 12 + 11] = 0;
  }
  uint4* dst = (uint4*)(Wt + (size_t)tid * 24);
  dst[0] = *(const uint4*)&buf[0];
  dst[1] = *(const uint4*)&buf[8];
  dst[2] = *(const uint4*)&buf[16];
}

// ---------------------------------------------------------------- CSR build
__global__ void k_count(const int* __restrict__ recv, int* __restrict__ cnt){
  int e = blockIdx.x * 256 + threadIdx.x;
  if(e < N_EDGES) atomicAdd(&cnt[recv[e]], 1);
}
__global__ void __launch_bounds__(1024) k_scan(const int* __restrict__ cnt, int* __restrict__ off){
  __shared__ int s[1024];
  int t = threadIdx.x;
  int base = t * 8;
  int loc[8]; int sum = 0;
  #pragma unroll
  for(int i = 0; i < 8; ++i){
    int idx = base + i;
    int v = (idx < N_NODES) ? cnt[idx] : 0;
    loc[i] = sum; sum += v;
  }
  s[t] = sum;
  __syncthreads();
  for(int d = 1; d < 1024; d <<= 1){
    int v = (t >= d) ? s[t - d] : 0;
    __syncthreads();
    s[t] += v;
    __syncthreads();
  }
  int excl = (t > 0) ? s[t - 1] : 0;
  #pragma unroll
  for(int i = 0; i < 8; ++i){
    int idx = base + i;
    if(idx <= N_NODES) off[idx] = excl + loc[i];
  }
}
__global__ void k_fill(const int* __restrict__ recv, const int* __restrict__ off,
                       int* __restrict__ cur, int* __restrict__ elist){
  int e = blockIdx.x * 256 + threadIdx.x;
  if(e < N_EDGES){
    int r = recv[e];
    int p = atomicAdd(&cur[r], 1);
    elist[off[r] + p] = e;
  }
}

// ---------------------------------------------------------------- K4: gather -> msg1[n][u][m]
// No LDS, no syncthreads: per-thread (u,mg) direct loads; e/snd prefetched 1 edge ahead.
// tpw: coalesced 8B/lane; x: coalesced 4B/lane; ea: wave-broadcast 2x float4.
__global__ void __launch_bounds__(256) k_gather(
    const __hip_bfloat16* __restrict__ tpw, const float* __restrict__ x,
    const float* __restrict__ ea, const int* __restrict__ send,
    const int* __restrict__ off, const int* __restrict__ elist,
    float* __restrict__ msg1){
  const int n = blockIdx.x, t = threadIdx.x;
  const int s0 = off[n], deg = off[n + 1] - s0;
  const int u = t & 127, mg = t >> 7;
  float acc[8] = {0.f,0.f,0.f,0.f,0.f,0.f,0.f,0.f};
  int e_nxt = 0, s_nxt = 0;
  if(deg > 0){ e_nxt = elist[s0]; s_nxt = send[e_nxt]; }
  for(int i = 0; i < deg; ++i){
    const int e = e_nxt, snd = s_nxt;
    if(i + 1 < deg){ e_nxt = elist[s0 + i + 1]; s_nxt = send[e_nxt]; }
    uint2 wp  = *(const uint2*)((const unsigned short*)tpw + (size_t)e * 512 + u * 4);
    float xu  = x[(size_t)snd * 128 + u];
    float4 e0 = *(const float4*)(ea + (size_t)e * 16 + mg * 8);
    float4 e1 = *(const float4*)(ea + (size_t)e * 16 + mg * 8 + 4);
    float w0 = lo2f(wp.x), w1 = hi2f(wp.x), w2 = lo2f(wp.y), w3 = hi2f(wp.y);
    if(mg == 0){                                    // m 0..7 : l = 0,1,1,1,2,2,2,2
      float a = w0 * xu, b = w1 * xu, c = w2 * xu;
      acc[0] += a * e0.x; acc[1] += b * e0.y; acc[2] += b * e0.z; acc[3] += b * e0.w;
      acc[4] += c * e1.x; acc[5] += c * e1.y; acc[6] += c * e1.z; acc[7] += c * e1.w;
    } else {                                        // m 8..15 : l = 2,3,3,3,3,3,3,3
      float c = w2 * xu, d = w3 * xu;
      acc[0] += c * e0.x; acc[1] += d * e0.y; acc[2] += d * e0.z; acc[3] += d * e0.w;
      acc[4] += d * e1.x; acc[5] += d * e1.y; acc[6] += d * e1.z; acc[7] += d * e1.w;
    }
  }
  float4* dst = (float4*)&msg1[(size_t)n * 2048 + u * 16 + mg * 8];
  dst[0] = make_float4(acc[0], acc[1], acc[2], acc[3]);
  dst[1] = make_float4(acc[4], acc[5], acc[6], acc[7]);
}

// ---------------------------------------------------------------- K5: msg2[n][u'][m] = sum_u msg1[n][u][m] * Wm[m][u][u']
__global__ void __launch_bounds__(256) k_lin(const float* __restrict__ msg1,
                                             const float* __restrict__ Wm,
                                             float* __restrict__ msg2){
  const int nb = blockIdx.x * 8;
  __shared__ float m1[8 * 2048];    // 64KB
  const int t = threadIdx.x;
  #pragma unroll
  for(int r = 0; r < 16; ++r){
    int i4 = t + 256 * r;
    ((float4*)m1)[i4] = ((const float4*)(msg1 + (size_t)nb * 2048))[i4];
  }
  __syncthreads();
  const int m = t & 15, g = t >> 4;
  float acc[8][8];
  #pragma unroll
  for(int a = 0; a < 8; ++a)
    #pragma unroll
    for(int b = 0; b < 8; ++b) acc[a][b] = 0.f;
  const float* Wp = Wm + m * 16384 + g * 8;
  for(int k = 0; k < 128; ++k){
    float4 wa = *(const float4*)(Wp + k * 128);
    float4 wb = *(const float4*)(Wp + k * 128 + 4);
    #pragma unroll
    for(int nl = 0; nl < 8; ++nl){
      float mv = m1[nl * 2048 + k * 16 + m];
      acc[nl][0] += mv * wa.x; acc[nl][1] += mv * wa.y;
      acc[nl][2] += mv * wa.z; acc[nl][3] += mv * wa.w;
      acc[nl][4] += mv * wb.x; acc[nl][5] += mv * wb.y;
      acc[nl][6] += mv * wb.z; acc[nl][7] += mv * wb.w;
    }
  }
  #pragma unroll
  for(int nl = 0; nl < 8; ++nl)
    #pragma unroll
    for(int j = 0; j < 8; ++j)
      msg2[(size_t)(nb + nl) * 2048 + (g * 8 + j) * 16 + m] = acc[nl][j];
}

// ---------------------------------------------------------------- K6: out[n][w][m] = NORM * sum_u msg2[n][u][m] * s(n,l(m),u,w)
// 512 thr = 128 w x 2 node-halves x 2 l-groups; 4 nodes/thread; NB=8/block, grid=1000.
// msg2 staged in LDS (64KB) once per block -> u-loop VMEM = 3 W loads only.
__global__ void __launch_bounds__(512, 4) k_skip(const float* __restrict__ msg2,
                                                 const float* __restrict__ attrs,
                                                 const unsigned short* __restrict__ Wt,
                                                 float* __restrict__ outp){
  const int nb = blockIdx.x * 8;
  const int t = threadIdx.x;
  __shared__ float m2s[8 * 2048];   // 64KB
  {
    const float4* src = (const float4*)(msg2 + (size_t)nb * 2048);
    float4* dstl = (float4*)m2s;
    #pragma unroll
    for(int r = 0; r < 8; ++r) dstl[t + 512 * r] = src[t + 512 * r];
  }
  const int w = t & 127;
  const int ng = t >> 7;            // 0..3, wave-uniform
  const int ngrp = ng & 1;          // node half: n0..n0+3
  const int lg = ng >> 1;           // 0: {l0,l3}   1: {l1,l2}
  const int n0 = nb + ngrp * 4;

  float av[4][10];
  #pragma unroll
  for(int j = 0; j < 4; ++j)
    #pragma unroll
    for(int v = 0; v < 10; ++v)
      av[j][v] = attrs[(size_t)(n0 + j) * 10 + v];

  __syncthreads();
  const float* m2p = m2s + (ngrp * 4) * 2048;
  const uint4* Wp = (const uint4*)(Wt + ((size_t)(lg * 128) * 128 + w) * 24);

  float acc[4][8];
  #pragma unroll
  for(int j = 0; j < 4; ++j)
    #pragma unroll
    for(int m = 0; m < 8; ++m) acc[j][m] = 0.f;

  #pragma unroll 2
  for(int u = 0; u < 128; ++u){
    uint4 a0 = Wp[(size_t)u * WT_U_STRIDE_U4 + 0];
    uint4 a1 = Wp[(size_t)u * WT_U_STRIDE_U4 + 1];
    uint4 a2 = Wp[(size_t)u * WT_U_STRIDE_U4 + 2];
    // pair A: v0..9 = a0 (8) + a1.x (2)
    float wa0 = lo2f(a0.x), wa1 = hi2f(a0.x), wa2 = lo2f(a0.y), wa3 = hi2f(a0.y);
    float wa4 = lo2f(a0.z), wa5 = hi2f(a0.z), wa6 = lo2f(a0.w), wa7 = hi2f(a0.w);
    float wa8 = lo2f(a1.x), wa9 = hi2f(a1.x);
    // pair B: v0,1 = a1.z; v2,3 = a1.w; v4..9 = a2.x,y,z
    float wb0 = lo2f(a1.z), wb1 = hi2f(a1.z), wb2 = lo2f(a1.w), wb3 = hi2f(a1.w);
    float wb4 = lo2f(a2.x), wb5 = hi2f(a2.x), wb6 = lo2f(a2.y), wb7 = hi2f(a2.y);
    float wb8 = lo2f(a2.z), wb9 = hi2f(a2.z);

    float sa[4], sb[4];
    #pragma unroll
    for(int j = 0; j < 4; ++j){
      float s = av[j][0]*wa0 + av[j][1]*wa1 + av[j][2]*wa2 + av[j][3]*wa3 + av[j][4]*wa4
              + av[j][5]*wa5 + av[j][6]*wa6 + av[j][7]*wa7 + av[j][8]*wa8 + av[j][9]*wa9;
      sa[j] = s;
      float r = av[j][0]*wb0 + av[j][1]*wb1 + av[j][2]*wb2 + av[j][3]*wb3 + av[j][4]*wb4
              + av[j][5]*wb5 + av[j][6]*wb6 + av[j][7]*wb7 + av[j][8]*wb8 + av[j][9]*wb9;
      sb[j] = r;
    }

    if(lg == 0){
      #pragma unroll
      for(int j = 0; j < 4; ++j){
        const float* q = m2p + (size_t)j * 2048 + u * 16;
        float  q00 = q[0];
        float4 q2 = *(const float4*)(q + 8);
        float4 q3 = *(const float4*)(q + 12);
        acc[j][0] += q00  * sa[j];                 // m0  (l0)
        acc[j][1] += q2.y * sb[j];                 // m9  (l3)
        acc[j][2] += q2.z * sb[j];                 // m10
        acc[j][3] += q2.w * sb[j];                 // m11
        acc[j][4] += q3.x * sb[j];                 // m12
        acc[j][5] += q3.y * sb[j];                 // m13
        acc[j][6] += q3.z * sb[j];                 // m14
        acc[j][7] += q3.w * sb[j];                 // m15
      }
    } else {
      #pragma unroll
      for(int j = 0; j < 4; ++j){
        const float* q = m2p + (size_t)j * 2048 + u * 16;
        float4 q0 = *(const float4*)q;
        float4 q1 = *(const float4*)(q + 4);
        float  q8 = q[8];
        acc[j][0] += q0.y * sa[j];                 // m1 (l1)
        acc[j][1] += q0.z * sa[j];                 // m2
        acc[j][2] += q0.w * sa[j];                 // m3
        acc[j][3] += q1.x * sb[j];                 // m4 (l2)
        acc[j][4] += q1.y * sb[j];                 // m5
        acc[j][5] += q1.z * sb[j];                 // m6
        acc[j][6] += q1.w * sb[j];                 // m7
        acc[j][7] += q8   * sb[j];                 // m8
      }
    }
  }

  if(lg == 0){
    #pragma unroll
    for(int j = 0; j < 4; ++j){
      float* dst = &outp[(size_t)(n0 + j) * 2048 + w * 16];
      dst[0] = acc[j][0] * NORM;
      dst[9] = acc[j][1] * NORM;
      float2 p2; p2.x = acc[j][2] * NORM; p2.y = acc[j][3] * NORM;
      *(float2*)(dst + 10) = p2;
      float4 p4;
      p4.x = acc[j][4] * NORM; p4.y = acc[j][5] * NORM;
      p4.z = acc[j][6] * NORM; p4.w = acc[j][7] * NORM;
      *(float4*)(dst + 12) = p4;
    }
  } else {
    #pragma unroll
    for(int j = 0; j < 4; ++j){
      float* dst = &outp[(size_t)(n0 + j) * 2048 + w * 16];
      dst[1] = acc[j][0] * NORM;
      float2 p2; p2.x = acc[j][1] * NORM; p2.y = acc[j][2] * NORM;
      *(float2*)(dst + 2) = p2;
      float4 p4;
      p4.x = acc[j][3] * NORM; p4.y = acc[j][4] * NORM;
      p4.z = acc[j][5] * NORM; p4.w = acc[j][6] * NORM;
      *(float4*)(dst + 4) = p4;
      dst[8] = acc[j][7] * NORM;
    }
  }
}

// ----------------------------------------------------------------
extern "C" void kernel_launch(void* const* d_in, const int* in_sizes, int n_in,
                              void* d_out, int out_size, void* d_ws, size_t ws_size,
                              hipStream_t stream){
  const float* node_attrs = (const float*)d_in[0];
  const float* node_feats = (const float*)d_in[1];
  const float* edge_attrs = (const float*)d_in[2];
  const float* edge_feats = (const float*)d_in[3];
  const int*   edge_index = (const int*)d_in[4];
  const float* cutoff     = (const float*)d_in[5];
  const float* W_up  = (const float*)d_in[6];
  const float* W1    = (const float*)d_in[7];
  const float* W2    = (const float*)d_in[8];
  const float* W3    = (const float*)d_in[9];
  const float* W4    = (const float*)d_in[10];
  const float* Wlin  = (const float*)d_in[11];
  const float* Wskip = (const float*)d_in[12];
  float* out = (float*)d_out;

  char* ws = (char*)d_ws;
  float*            x     = (float*)(ws + 0);
  __hip_bfloat16*   tpw   = (__hip_bfloat16*)(ws + 4096000);
  float*            msg2  = (float*)(ws + 4096000);       // overlays tpw (dead after k_gather)
  float*            msg1  = (float*)(ws + 135168000);
  unsigned short*   Wt16  = (unsigned short*)(ws + 135168000); // overlays msg1 (dead after k_lin)
  float*            Wm    = (float*)(ws + 200704000);
  int*              cnt   = (int*)(ws + 201752576);
  int*              cur   = (int*)(ws + 201784576);
  int*              offs  = (int*)(ws + 201816576);       // 8001 ints
  int*              elist = (int*)(ws + 201848640);       // 128000 ints

  hipMemsetAsync(cnt, 0, 64000, stream);  // cnt + cur

  k_up    <<<4000, 256, 0, stream>>>(node_feats, W_up, x);
  k_mlp   <<<2000, 256, 0, stream>>>(edge_feats, cutoff, W1, W2, W3, W4, tpw);
  k_wm    <<<1024, 256, 0, stream>>>(Wlin, Wm);
  k_count <<<500,  256, 0, stream>>>(edge_index + N_EDGES, cnt);
  k_scan  <<<1,   1024, 0, stream>>>(cnt, offs);
  k_fill  <<<500,  256, 0, stream>>>(edge_index + N_EDGES, offs, cur, elist);
  k_gather<<<8000, 256, 0, stream>>>(tpw, x, edge_attrs, edge_index, offs, elist, msg1);
  k_lin   <<<1000, 256, 0, stream>>>(msg1, Wm, msg2);
  k_wcvt  <<<128,  256, 0, stream>>>(Wskip, Wt16);        // after k_lin: Wt16 overlays msg1
  k_skip  <<<1000, 512, 0, stream>>>(msg2, node_attrs, Wt16, out);
}

// Round 8
// 874.073 us; speedup vs baseline: 4.2118x; 4.2118x over previous
//
#include <hip/hip_runtime.h>
#include <hip/hip_bf16.h>

#define N_NODES 8000
#define N_EDGES 128000
#define RS8   0.35355339059327373f
#define RS64  0.125f
#define RS128 0.08838834764831845f
#define C1    0.005524271728019903f   /* (1/sqrt(128))/16 */
#define NORM  0.02795084971874737f    /* 1/sqrt(1280) */

__device__ __forceinline__ float siluf(float v){ return v / (1.f + __expf(-v)); }
__device__ __forceinline__ unsigned short f2bf(float v){
  unsigned int b = __float_as_uint(v);
  b += 0x7fffu + ((b >> 16) & 1u);
  return (unsigned short)(b >> 16);
}
__device__ __forceinline__ float bf2f(unsigned int h){
  union{unsigned int u; float f;} z; z.u = h << 16; return z.f;
}
__device__ __forceinline__ float lo2f(unsigned int p){  // low bf16 of packed u32
  union{unsigned int u; float f;} z; z.u = p << 16; return z.f;
}
__device__ __forceinline__ float hi2f(unsigned int p){  // high bf16 of packed u32
  union{unsigned int u; float f;} z; z.u = p & 0xffff0000u; return z.f;
}

// Wt element = 24 ushorts (48 B) per (lg,u,w); per-u stride = 128 w * 48 B = 6144 B.
#define WT_U_STRIDE_U4 384   /* 6144 / sizeof(uint4) */

// ---------------------------------------------------------------- K1: x = node_feats @ W_up * RS128
__global__ void __launch_bounds__(256) k_up(const float* __restrict__ nf,
                                            const float* __restrict__ Wup,
                                            float* __restrict__ x){
  __shared__ float f[2][128];
  const int t = threadIdx.x;
  const int nl = t >> 7, c = t & 127;
  const int n = blockIdx.x * 2 + nl;
  f[nl][c] = nf[(size_t)n * 128 + c];
  __syncthreads();
  float acc = 0.f;
  #pragma unroll 8
  for(int k = 0; k < 128; ++k) acc += f[nl][k] * Wup[k * 128 + c];
  x[(size_t)n * 128 + c] = acc * RS128;
}

// ---------------------------------------------------------------- K2: edge MLP -> tp_weights (bf16, cutoff folded)
__device__ __forceinline__ void gemm64(const float* __restrict__ hin, const float* __restrict__ Wb,
                                       int eb, int cb, float4 acc[4]){
  #pragma unroll
  for(int i = 0; i < 4; ++i) acc[i] = make_float4(0.f,0.f,0.f,0.f);
  #pragma unroll 2
  for(int k = 0; k < 64; k += 4){
    float4 w0 = *(const float4*)&Wb[(k+0)*64 + cb];
    float4 w1 = *(const float4*)&Wb[(k+1)*64 + cb];
    float4 w2 = *(const float4*)&Wb[(k+2)*64 + cb];
    float4 w3 = *(const float4*)&Wb[(k+3)*64 + cb];
    #pragma unroll
    for(int i = 0; i < 4; ++i){
      float4 h = *(const float4*)&hin[(eb+i)*64 + k];
      acc[i].x += h.x*w0.x + h.y*w1.x + h.z*w2.x + h.w*w3.x;
      acc[i].y += h.x*w0.y + h.y*w1.y + h.z*w2.y + h.w*w3.y;
      acc[i].z += h.x*w0.z + h.y*w1.z + h.z*w2.z + h.w*w3.z;
      acc[i].w += h.x*w0.w + h.y*w1.w + h.z*w2.w + h.w*w3.w;
    }
  }
}

__global__ void __launch_bounds__(256) k_mlp(
    const float* __restrict__ efg, const float* __restrict__ cut,
    const float* __restrict__ W1g, const float* __restrict__ W2g,
    const float* __restrict__ W3g, const float* __restrict__ W4g,
    __hip_bfloat16* __restrict__ tpw){
  __shared__ float ef[512];     // 64 edges x 8
  __shared__ float W1s[512];
  __shared__ float hA[4096];    // 64 x 64
  __shared__ float hB[4096];
  __shared__ float Wb[4096];
  __shared__ float co[64];
  const int t = threadIdx.x;
  const int e0 = blockIdx.x * 64;
  ((float2*)ef)[t]  = ((const float2*)(efg + (size_t)e0 * 8))[t];
  ((float2*)W1s)[t] = ((const float2*)W1g)[t];
  if(t < 64) co[t] = cut[e0 + t];
  __syncthreads();
  const int et = t >> 4, ct = t & 15;
  const int eb = et * 4, cb = ct * 4;
  // L1: (64x8)@(8x64) * RS8 -> silu -> hA
  {
    float4 acc[4];
    #pragma unroll
    for(int i = 0; i < 4; ++i) acc[i] = make_float4(0.f,0.f,0.f,0.f);
    #pragma unroll
    for(int k = 0; k < 8; ++k){
      float4 wv = *(const float4*)&W1s[k*64 + cb];
      #pragma unroll
      for(int i = 0; i < 4; ++i){
        float h = ef[(eb+i)*8 + k];
        acc[i].x += h*wv.x; acc[i].y += h*wv.y; acc[i].z += h*wv.z; acc[i].w += h*wv.w;
      }
    }
    #pragma unroll
    for(int i = 0; i < 4; ++i){
      float4 r;
      r.x = siluf(acc[i].x*RS8); r.y = siluf(acc[i].y*RS8);
      r.z = siluf(acc[i].z*RS8); r.w = siluf(acc[i].w*RS8);
      *(float4*)&hA[(eb+i)*64 + cb] = r;
    }
  }
  __syncthreads();
  #pragma unroll
  for(int r = 0; r < 8; ++r) ((float2*)Wb)[t + 256*r] = ((const float2*)W2g)[t + 256*r];
  __syncthreads();
  { // L2: hA -> hB
    float4 a[4]; gemm64(hA, Wb, eb, cb, a);
    #pragma unroll
    for(int i = 0; i < 4; ++i){
      float4 r;
      r.x = siluf(a[i].x*RS64); r.y = siluf(a[i].y*RS64);
      r.z = siluf(a[i].z*RS64); r.w = siluf(a[i].w*RS64);
      *(float4*)&hB[(eb+i)*64 + cb] = r;
    }
  }
  __syncthreads();
  #pragma unroll
  for(int r = 0; r < 8; ++r) ((float2*)Wb)[t + 256*r] = ((const float2*)W3g)[t + 256*r];
  __syncthreads();
  { // L3: hB -> hA
    float4 a[4]; gemm64(hB, Wb, eb, cb, a);
    #pragma unroll
    for(int i = 0; i < 4; ++i){
      float4 r;
      r.x = siluf(a[i].x*RS64); r.y = siluf(a[i].y*RS64);
      r.z = siluf(a[i].z*RS64); r.w = siluf(a[i].w*RS64);
      *(float4*)&hA[(eb+i)*64 + cb] = r;
    }
  }
  __syncthreads();
  // L4: hA(64x64) @ W4(64x512) in 8 chunks of 64 cols; *RS64*cutoff -> bf16
  for(int ch = 0; ch < 8; ++ch){
    #pragma unroll
    for(int r = 0; r < 16; ++r){
      int idx = t + 256*r;
      Wb[idx] = W4g[(idx >> 6) * 512 + ch * 64 + (idx & 63)];
    }
    __syncthreads();
    float4 a[4]; gemm64(hA, Wb, eb, cb, a);
    #pragma unroll
    for(int i = 0; i < 4; ++i){
      float cf = co[eb + i] * RS64;
      ushort4 pk;
      pk.x = f2bf(a[i].x * cf); pk.y = f2bf(a[i].y * cf);
      pk.z = f2bf(a[i].z * cf); pk.w = f2bf(a[i].w * cf);
      *(ushort4*)((unsigned short*)tpw + (size_t)(e0 + eb + i) * 512 + ch * 64 + cb) = pk;
    }
    __syncthreads();
  }
}

// ---------------------------------------------------------------- Wm[m][u][u'] = W_lin[l(m)][u][u'] * C1
__global__ void k_wm(const float* __restrict__ Wlin, float* __restrict__ Wm){
  int idx = blockIdx.x * 256 + threadIdx.x;
  if(idx >= 16 * 16384) return;
  int m = idx >> 14;
  int l = (m == 0) ? 0 : (m < 4) ? 1 : (m < 9) ? 2 : 3;
  Wm[idx] = Wlin[l * 16384 + (idx & 16383)] * C1;
}

// ---------------------------------------------------------------- W_skip -> transposed bf16
// Wt[lg][u][w][p][12v] ushort, lg0 pairs (l0,l3), lg1 pairs (l1,l2); v=10,11 zero pad.
__global__ void __launch_bounds__(256) k_wcvt(const float* __restrict__ Ws,
                                              unsigned short* __restrict__ Wt){
  int tid = blockIdx.x * 256 + threadIdx.x;   // 32768 = 2 lg * 128 u * 128 w
  int lg = tid >> 14, u = (tid >> 7) & 127, w = tid & 127;
  unsigned short buf[24];
  #pragma unroll
  for(int p = 0; p < 2; ++p){
    int l = (lg == 0) ? (p == 0 ? 0 : 3) : (p == 0 ? 1 : 2);
    #pragma unroll
    for(int v = 0; v < 10; ++v)
      buf[p * 12 + v] = f2bf(Ws[((size_t)(l * 128 + u) * 10 + v) * 128 + w]);
    buf[p * 12 + 10] = 0; buf[p * 12 + 11] = 0;
  }
  uint4* dst = (uint4*)(Wt + (size_t)tid * 24);
  dst[0] = *(const uint4*)&buf[0];
  dst[1] = *(const uint4*)&buf[8];
  dst[2] = *(const uint4*)&buf[16];
}

// ---------------------------------------------------------------- CSR build
__global__ void k_count(const int* __restrict__ recv, int* __restrict__ cnt){
  int e = blockIdx.x * 256 + threadIdx.x;
  if(e < N_EDGES) atomicAdd(&cnt[recv[e]], 1);
}
__global__ void __launch_bounds__(1024) k_scan(const int* __restrict__ cnt, int* __restrict__ off){
  __shared__ int s[1024];
  int t = threadIdx.x;
  int base = t * 8;
  int loc[8]; int sum = 0;
  #pragma unroll
  for(int i = 0; i < 8; ++i){
    int idx = base + i;
    int v = (idx < N_NODES) ? cnt[idx] : 0;
    loc[i] = sum; sum += v;
  }
  s[t] = sum;
  __syncthreads();
  for(int d = 1; d < 1024; d <<= 1){
    int v = (t >= d) ? s[t - d] : 0;
    __syncthreads();
    s[t] += v;
    __syncthreads();
  }
  int excl = (t > 0) ? s[t - 1] : 0;
  #pragma unroll
  for(int i = 0; i < 8; ++i){
    int idx = base + i;
    if(idx <= N_NODES) off[idx] = excl + loc[i];
  }
}
__global__ void k_fill(const int* __restrict__ recv, const int* __restrict__ off,
                       int* __restrict__ cur, int* __restrict__ elist){
  int e = blockIdx.x * 256 + threadIdx.x;
  if(e < N_EDGES){
    int r = recv[e];
    int p = atomicAdd(&cur[r], 1);
    elist[off[r] + p] = e;
  }
}

// ---------------------------------------------------------------- K4: gather -> msg1[n][u][m]
// No LDS, no syncthreads: per-thread (u,mg) direct loads; e/snd prefetched 1 edge ahead.
__global__ void __launch_bounds__(256) k_gather(
    const __hip_bfloat16* __restrict__ tpw, const float* __restrict__ x,
    const float* __restrict__ ea, const int* __restrict__ send,
    const int* __restrict__ off, const int* __restrict__ elist,
    float* __restrict__ msg1){
  const int n = blockIdx.x, t = threadIdx.x;
  const int s0 = off[n], deg = off[n + 1] - s0;
  const int u = t & 127, mg = t >> 7;
  float acc[8] = {0.f,0.f,0.f,0.f,0.f,0.f,0.f,0.f};
  int e_nxt = 0, s_nxt = 0;
  if(deg > 0){ e_nxt = elist[s0]; s_nxt = send[e_nxt]; }
  for(int i = 0; i < deg; ++i){
    const int e = e_nxt, snd = s_nxt;
    if(i + 1 < deg){ e_nxt = elist[s0 + i + 1]; s_nxt = send[e_nxt]; }
    uint2 wp  = *(const uint2*)((const unsigned short*)tpw + (size_t)e * 512 + u * 4);
    float xu  = x[(size_t)snd * 128 + u];
    float4 e0 = *(const float4*)(ea + (size_t)e * 16 + mg * 8);
    float4 e1 = *(const float4*)(ea + (size_t)e * 16 + mg * 8 + 4);
    float w0 = lo2f(wp.x), w1 = hi2f(wp.x), w2 = lo2f(wp.y), w3 = hi2f(wp.y);
    if(mg == 0){                                    // m 0..7 : l = 0,1,1,1,2,2,2,2
      float a = w0 * xu, b = w1 * xu, c = w2 * xu;
      acc[0] += a * e0.x; acc[1] += b * e0.y; acc[2] += b * e0.z; acc[3] += b * e0.w;
      acc[4] += c * e1.x; acc[5] += c * e1.y; acc[6] += c * e1.z; acc[7] += c * e1.w;
    } else {                                        // m 8..15 : l = 2,3,3,3,3,3,3,3
      float c = w2 * xu, d = w3 * xu;
      acc[0] += c * e0.x; acc[1] += d * e0.y; acc[2] += d * e0.z; acc[3] += d * e0.w;
      acc[4] += d * e1.x; acc[5] += d * e1.y; acc[6] += d * e1.z; acc[7] += d * e1.w;
    }
  }
  float4* dst = (float4*)&msg1[(size_t)n * 2048 + u * 16 + mg * 8];
  dst[0] = make_float4(acc[0], acc[1], acc[2], acc[3]);
  dst[1] = make_float4(acc[4], acc[5], acc[6], acc[7]);
}

// ---------------------------------------------------------------- K5: msg2[n][u'][m] = sum_u msg1[n][u][m] * Wm[m][u][u']
__global__ void __launch_bounds__(256) k_lin(const float* __restrict__ msg1,
                                             const float* __restrict__ Wm,
                                             float* __restrict__ msg2){
  const int nb = blockIdx.x * 8;
  __shared__ float m1[8 * 2048];    // 64KB
  const int t = threadIdx.x;
  #pragma unroll
  for(int r = 0; r < 16; ++r){
    int i4 = t + 256 * r;
    ((float4*)m1)[i4] = ((const float4*)(msg1 + (size_t)nb * 2048))[i4];
  }
  __syncthreads();
  const int m = t & 15, g = t >> 4;
  float acc[8][8];
  #pragma unroll
  for(int a = 0; a < 8; ++a)
    #pragma unroll
    for(int b = 0; b < 8; ++b) acc[a][b] = 0.f;
  const float* Wp = Wm + m * 16384 + g * 8;
  for(int k = 0; k < 128; ++k){
    float4 wa = *(const float4*)(Wp + k * 128);
    float4 wb = *(const float4*)(Wp + k * 128 + 4);
    #pragma unroll
    for(int nl = 0; nl < 8; ++nl){
      float mv = m1[nl * 2048 + k * 16 + m];
      acc[nl][0] += mv * wa.x; acc[nl][1] += mv * wa.y;
      acc[nl][2] += mv * wa.z; acc[nl][3] += mv * wa.w;
      acc[nl][4] += mv * wb.x; acc[nl][5] += mv * wb.y;
      acc[nl][6] += mv * wb.z; acc[nl][7] += mv * wb.w;
    }
  }
  #pragma unroll
  for(int nl = 0; nl < 8; ++nl)
    #pragma unroll
    for(int j = 0; j < 8; ++j)
      msg2[(size_t)(nb + nl) * 2048 + (g * 8 + j) * 16 + m] = acc[nl][j];
}

// ---------------------------------------------------------------- K6: out[n][w][m] = NORM * sum_u msg2[n][u][m] * s(n,l(m),u,w)
// 512 thr = 128 w x 2 node-halves x 2 l-groups; 4 nodes/thread; NB=8/block, grid=1000.
// msg2 staged in LDS (64KB) once per block -> u-loop VMEM = 3 W loads only.
// launch_bounds(512,2): VGPR budget 256 — do NOT request more waves (R6: ',4' forced
// a 64-VGPR allocation and spilled the accumulators -> 9.6GB scratch traffic, 5.6x slower).
__global__ void __launch_bounds__(512, 2) k_skip(const float* __restrict__ msg2,
                                                 const float* __restrict__ attrs,
                                                 const unsigned short* __restrict__ Wt,
                                                 float* __restrict__ outp){
  const int nb = blockIdx.x * 8;
  const int t = threadIdx.x;
  __shared__ float m2s[8 * 2048];   // 64KB
  {
    const float4* src = (const float4*)(msg2 + (size_t)nb * 2048);
    float4* dstl = (float4*)m2s;
    #pragma unroll
    for(int r = 0; r < 8; ++r) dstl[t + 512 * r] = src[t + 512 * r];
  }
  const int w = t & 127;
  const int ng = t >> 7;            // 0..3, wave-uniform
  const int ngrp = ng & 1;          // node half: n0..n0+3
  const int lg = ng >> 1;           // 0: {l0,l3}   1: {l1,l2}
  const int n0 = nb + ngrp * 4;

  float av[4][10];
  #pragma unroll
  for(int j = 0; j < 4; ++j)
    #pragma unroll
    for(int v = 0; v < 10; ++v)
      av[j][v] = attrs[(size_t)(n0 + j) * 10 + v];

  __syncthreads();
  const float* m2p = m2s + (ngrp * 4) * 2048;
  const uint4* Wp = (const uint4*)(Wt + ((size_t)(lg * 128) * 128 + w) * 24);

  float acc[4][8];
  #pragma unroll
  for(int j = 0; j < 4; ++j)
    #pragma unroll
    for(int m = 0; m < 8; ++m) acc[j][m] = 0.f;

  #pragma unroll 2
  for(int u = 0; u < 128; ++u){
    uint4 a0 = Wp[(size_t)u * WT_U_STRIDE_U4 + 0];
    uint4 a1 = Wp[(size_t)u * WT_U_STRIDE_U4 + 1];
    uint4 a2 = Wp[(size_t)u * WT_U_STRIDE_U4 + 2];
    // pair A: v0..9 = a0 (8) + a1.x (2)
    float wa0 = lo2f(a0.x), wa1 = hi2f(a0.x), wa2 = lo2f(a0.y), wa3 = hi2f(a0.y);
    float wa4 = lo2f(a0.z), wa5 = hi2f(a0.z), wa6 = lo2f(a0.w), wa7 = hi2f(a0.w);
    float wa8 = lo2f(a1.x), wa9 = hi2f(a1.x);
    // pair B: v0,1 = a1.z; v2,3 = a1.w; v4..9 = a2.x,y,z
    float wb0 = lo2f(a1.z), wb1 = hi2f(a1.z), wb2 = lo2f(a1.w), wb3 = hi2f(a1.w);
    float wb4 = lo2f(a2.x), wb5 = hi2f(a2.x), wb6 = lo2f(a2.y), wb7 = hi2f(a2.y);
    float wb8 = lo2f(a2.z), wb9 = hi2f(a2.z);

    float sa[4], sb[4];
    #pragma unroll
    for(int j = 0; j < 4; ++j){
      float s = av[j][0]*wa0 + av[j][1]*wa1 + av[j][2]*wa2 + av[j][3]*wa3 + av[j][4]*wa4
              + av[j][5]*wa5 + av[j][6]*wa6 + av[j][7]*wa7 + av[j][8]*wa8 + av[j][9]*wa9;
      sa[j] = s;
      float r = av[j][0]*wb0 + av[j][1]*wb1 + av[j][2]*wb2 + av[j][3]*wb3 + av[j][4]*wb4
              + av[j][5]*wb5 + av[j][6]*wb6 + av[j][7]*wb7 + av[j][8]*wb8 + av[j][9]*wb9;
      sb[j] = r;
    }

    if(lg == 0){
      #pragma unroll
      for(int j = 0; j < 4; ++j){
        const float* q = m2p + (size_t)j * 2048 + u * 16;
        float  q00 = q[0];
        float4 q2 = *(const float4*)(q + 8);
        float4 q3 = *(const float4*)(q + 12);
        acc[j][0] += q00  * sa[j];                 // m0  (l0)
        acc[j][1] += q2.y * sb[j];                 // m9  (l3)
        acc[j][2] += q2.z * sb[j];                 // m10
        acc[j][3] += q2.w * sb[j];                 // m11
        acc[j][4] += q3.x * sb[j];                 // m12
        acc[j][5] += q3.y * sb[j];                 // m13
        acc[j][6] += q3.z * sb[j];                 // m14
        acc[j][7] += q3.w * sb[j];                 // m15
      }
    } else {
      #pragma unroll
      for(int j = 0; j < 4; ++j){
        const float* q = m2p + (size_t)j * 2048 + u * 16;
        float4 q0 = *(const float4*)q;
        float4 q1 = *(const float4*)(q + 4);
        float  q8 = q[8];
        acc[j][0] += q0.y * sa[j];                 // m1 (l1)
        acc[j][1] += q0.z * sa[j];                 // m2
        acc[j][2] += q0.w * sa[j];                 // m3
        acc[j][3] += q1.x * sb[j];                 // m4 (l2)
        acc[j][4] += q1.y * sb[j];                 // m5
        acc[j][5] += q1.z * sb[j];                 // m6
        acc[j][6] += q1.w * sb[j];                 // m7
        acc[j][7] += q8   * sb[j];                 // m8
      }
    }
  }

  if(lg == 0){
    #pragma unroll
    for(int j = 0; j < 4; ++j){
      float* dst = &outp[(size_t)(n0 + j) * 2048 + w * 16];
      dst[0] = acc[j][0] * NORM;
      dst[9] = acc[j][1] * NORM;
      float2 p2; p2.x = acc[j][2] * NORM; p2.y = acc[j][3] * NORM;
      *(float2*)(dst + 10) = p2;
      float4 p4;
      p4.x = acc[j][4] * NORM; p4.y = acc[j][5] * NORM;
      p4.z = acc[j][6] * NORM; p4.w = acc[j][7] * NORM;
      *(float4*)(dst + 12) = p4;
    }
  } else {
    #pragma unroll
    for(int j = 0; j < 4; ++j){
      float* dst = &outp[(size_t)(n0 + j) * 2048 + w * 16];
      dst[1] = acc[j][0] * NORM;
      float2 p2; p2.x = acc[j][1] * NORM; p2.y = acc[j][2] * NORM;
      *(float2*)(dst + 2) = p2;
      float4 p4;
      p4.x = acc[j][3] * NORM; p4.y = acc[j][4] * NORM;
      p4.z = acc[j][5] * NORM; p4.w = acc[j][6] * NORM;
      *(float4*)(dst + 4) = p4;
      dst[8] = acc[j][7] * NORM;
    }
  }
}

// ----------------------------------------------------------------
extern "C" void kernel_launch(void* const* d_in, const int* in_sizes, int n_in,
                              void* d_out, int out_size, void* d_ws, size_t ws_size,
                              hipStream_t stream){
  const float* node_attrs = (const float*)d_in[0];
  const float* node_feats = (const float*)d_in[1];
  const float* edge_attrs = (const float*)d_in[2];
  const float* edge_feats = (const float*)d_in[3];
  const int*   edge_index = (const int*)d_in[4];
  const float* cutoff     = (const float*)d_in[5];
  const float* W_up  = (const float*)d_in[6];
  const float* W1    = (const float*)d_in[7];
  const float* W2    = (const float*)d_in[8];
  const float* W3    = (const float*)d_in[9];
  const float* W4    = (const float*)d_in[10];
  const float* Wlin  = (const float*)d_in[11];
  const float* Wskip = (const float*)d_in[12];
  float* out = (float*)d_out;

  char* ws = (char*)d_ws;
  float*            x     = (float*)(ws + 0);
  __hip_bfloat16*   tpw   = (__hip_bfloat16*)(ws + 4096000);
  float*            msg2  = (float*)(ws + 4096000);       // overlays tpw (dead after k_gather)
  float*            msg1  = (float*)(ws + 135168000);
  unsigned short*   Wt16  = (unsigned short*)(ws + 135168000); // overlays msg1 (dead after k_lin)
  float*            Wm    = (float*)(ws + 200704000);
  int*              cnt   = (int*)(ws + 201752576);
  int*              cur   = (int*)(ws + 201784576);
  int*              offs  = (int*)(ws + 201816576);       // 8001 ints
  int*              elist = (int*)(ws + 201848640);       // 128000 ints

  hipMemsetAsync(cnt, 0, 64000, stream);  // cnt + cur

  k_up    <<<4000, 256, 0, stream>>>(node_feats, W_up, x);
  k_mlp   <<<2000, 256, 0, stream>>>(edge_feats, cutoff, W1, W2, W3, W4, tpw);
  k_wm    <<<1024, 256, 0, stream>>>(Wlin, Wm);
  k_count <<<500,  256, 0, stream>>>(edge_index + N_EDGES, cnt);
  k_scan  <<<1,   1024, 0, stream>>>(cnt, offs);
  k_fill  <<<500,  256, 0, stream>>>(edge_index + N_EDGES, offs, cur, elist);
  k_gather<<<8000, 256, 0, stream>>>(tpw, x, edge_attrs, edge_index, offs, elist, msg1);
  k_lin   <<<1000, 256, 0, stream>>>(msg1, Wm, msg2);
  k_wcvt  <<<128,  256, 0, stream>>>(Wskip, Wt16);        // after k_lin: Wt16 overlays msg1
  k_skip  <<<1000, 512, 0, stream>>>(msg2, node_attrs, Wt16, out);
}